// Round 5
// baseline (314.256 us; speedup 1.0000x reference)
//
#include <hip/hip_runtime.h>

// TimeConcater: new_x[b,p,d] = sum_l [bucket(ts[b,l])==p] * x[b,l,d]
// B=32, L=4096, D=256, P=32 buckets over np.linspace(0,1.001,33) edges.
// Output flat: new_x (32,32,256), then time_steps (32,4096).
//
// R4: row-major sequential streaming (optimal DRAM pattern), scatter into
// LDS bucket accumulators with ds_add_f32 (no-return LDS atomics), flush via
// global atomicAdd onto a zeroed output. High occupancy (16 waves/CU) +
// 8-deep load unroll (8 KB in flight per wave) hides HBM latency; R0's
// failure mode (1 block/CU, per-row vmcnt(0) stalls) is removed.

#define Bk 32
#define Lk 4096
#define Dk 256
#define Pk 32
#define NT 512            // threads/block (8 waves)
#define CHUNK 256         // rows per block
#define RPW (CHUNK / 8)   // rows per wave = 32

__device__ __forceinline__ int bucket_of(float tv) {
    // Emulate np.linspace(0.0, 1.001, 33): edge(i) = float32((double)i * (1.001/32))
    const double step = 1.001 / 32.0;
    int p = (int)(tv * (float)(32.0 / 1.001));
    p = p < 0 ? 0 : (p > 31 ? 31 : p);
    while (p > 0 && tv < (float)((double)p * step)) --p;
    while (p < 31 && tv >= (float)((double)(p + 1) * step)) ++p;
    return p;
}

__global__ __launch_bounds__(NT, 4) void tc_stream(
        const float* __restrict__ x,
        const float* __restrict__ ts,
        float* __restrict__ out,
        float* __restrict__ ts_out) {
    __shared__ float acc[Pk * Dk];   // 32 KB bucket accumulators
    __shared__ int sbuck[CHUNK];     // per-row bucket

    const int c = blockIdx.x;        // chunk 0..15
    const int b = blockIdx.y;        // batch 0..31
    const int t = threadIdx.x;
    const int w = t >> 6;            // wave 0..7
    const int lane = t & 63;
    const int col4 = lane << 2;      // lane's 4 columns
    const int l0 = c * CHUNK;

    // Zero accumulators (8192 floats / 512 threads = 16 each).
#pragma unroll
    for (int k = 0; k < (Pk * Dk) / NT; ++k)
        acc[t + k * NT] = 0.0f;

    // Buckets for this chunk's 256 rows + ts passthrough for this slice.
    if (t < CHUNK) {
        const float tv = ts[(size_t)b * Lk + l0 + t];
        ts_out[(size_t)b * Lk + l0 + t] = tv;
        sbuck[t] = bucket_of(tv);
    }
    __syncthreads();

    // Stream: wave w owns rows [w*RPW, (w+1)*RPW) of the chunk — contiguous
    // 32 KB per wave, read once, in order. 8-deep unroll => 8 outstanding
    // 1 KB global_load_dwordx4 per wave before the first waitcnt.
    const float* xp = x + ((size_t)b * Lk + l0) * Dk;
    const int rbase = w * RPW;
    for (int i0 = 0; i0 < RPW; i0 += 8) {
        float4 v[8];
#pragma unroll
        for (int j = 0; j < 8; ++j)
            v[j] = *(const float4*)(xp + (size_t)(rbase + i0 + j) * Dk + col4);
#pragma unroll
        for (int j = 0; j < 8; ++j) {
            float* a = &acc[sbuck[rbase + i0 + j] * Dk + col4];
            atomicAdd(&a[0], v[j].x);   // ds_add_f32, no-return
            atomicAdd(&a[1], v[j].y);
            atomicAdd(&a[2], v[j].z);
            atomicAdd(&a[3], v[j].w);
        }
    }
    __syncthreads();

    // Flush block-local bucket sums into global out (zeroed by memset node).
    float* ob = out + (size_t)b * (Pk * Dk);
#pragma unroll
    for (int k = 0; k < (Pk * Dk) / NT; ++k) {
        const int idx = t + k * NT;
        atomicAdd(&ob[idx], acc[idx]);
    }
}

extern "C" void kernel_launch(void* const* d_in, const int* in_sizes, int n_in,
                              void* d_out, int out_size, void* d_ws, size_t ws_size,
                              hipStream_t stream) {
    const float* x  = (const float*)d_in[0];
    const float* ts = (const float*)d_in[1];
    float* out = (float*)d_out;
    float* ts_out = out + (size_t)Bk * Pk * Dk;

    // Zero new_x region (flush atomics accumulate onto it).
    hipMemsetAsync(out, 0, (size_t)Bk * Pk * Dk * sizeof(float), stream);

    dim3 grid(Lk / CHUNK, Bk);   // (16, 32) = 512 blocks
    tc_stream<<<grid, NT, 0, stream>>>(x, ts, out, ts_out);
}